// Round 4
// baseline (185.919 us; speedup 1.0000x reference)
//
#include <hip/hip_runtime.h>
#include <math.h>

#define EPS 1.1920928955078125e-07f   // jnp.finfo(f32).eps

typedef __attribute__((ext_vector_type(8)))  short short8;
typedef __attribute__((ext_vector_type(4)))  short short4v;
typedef __attribute__((ext_vector_type(16))) float floatx16;

__device__ __forceinline__ float4 ld4(const float* __restrict__ p) { return *(const float4* __restrict__)p; }
__device__ __forceinline__ void   st4(float* __restrict__ p, float4 v) { *(float4* __restrict__)p = v; }

// f32 -> bf16 round-to-nearest-even (bit pattern in ushort)
__device__ __forceinline__ unsigned short f2bf(float f) {
    union { float f; unsigned u; } v; v.f = f;
    unsigned r = v.u + 0x7fffu + ((v.u >> 16) & 1u);
    return (unsigned short)(r >> 16);
}

// ---------------------------------------------------------------------------
// Kernel 1a: pack W_cat rows into MFMA B-fragment layout, bf16 (as round 3).
// WbF[((nt*16 + ks)*64 + lane)*8 + j] = W_cat[nt*32+(lane&31)][ks*16+(lane>>5)*8+j]
// ---------------------------------------------------------------------------
__global__ __launch_bounds__(256) void build_wb(const float* __restrict__ val_W,
                                                const float* __restrict__ key_W,
                                                unsigned short* __restrict__ WbF)
{
    int idx  = blockIdx.x * 256 + threadIdx.x;    // 0 .. 20479
    int lane = idx & 63;
    int ks   = (idx >> 6) & 15;
    int nt   = idx >> 10;                         // 0..19
    int n = (nt << 5) + (lane & 31);
    int k = (ks << 4) + ((lane >> 5) << 3);
    const float* src = (n < 512) ? key_W + (size_t)n * 256 + k
                                 : val_W + (size_t)(n - 512) * 256 + k;
    float4 v0 = ld4(src), v1 = ld4(src + 4);
    unsigned short o[8] = { f2bf(v0.x), f2bf(v0.y), f2bf(v0.z), f2bf(v0.w),
                            f2bf(v1.x), f2bf(v1.y), f2bf(v1.z), f2bf(v1.w) };
    unsigned short* dst = WbF + (size_t)idx * 8;
    *(short4v*)dst       = *(short4v*)&o[0];
    *(short4v*)(dst + 4) = *(short4v*)&o[4];
}

// ---------------------------------------------------------------------------
// Kernel 1b: embedding table f32 -> bf16 (done once; removes f2bf from hot loop)
// ---------------------------------------------------------------------------
__global__ __launch_bounds__(256) void build_ebf(const float* __restrict__ emb,
                                                 unsigned short* __restrict__ ebf)
{
    int idx = blockIdx.x * 256 + threadIdx.x;     // < 131072, 8 floats each
    const float* src = emb + ((size_t)idx << 3);
    float4 v0 = ld4(src), v1 = ld4(src + 4);
    unsigned short o[8] = { f2bf(v0.x), f2bf(v0.y), f2bf(v0.z), f2bf(v0.w),
                            f2bf(v1.x), f2bf(v1.y), f2bf(v1.z), f2bf(v1.w) };
    unsigned short* dst = ebf + ((size_t)idx << 3);
    *(short4v*)dst       = *(short4v*)&o[0];
    *(short4v*)(dst + 4) = *(short4v*)&o[4];
}

// ---------------------------------------------------------------------------
// Kernel 2: hash + gather(bf16) + MFMA GEMM, 32-token tile, ALL 5 chunks/block
// grid 1024, 256 threads (4 waves). Wave wv: n-subtile wv of every chunk j:
// n-tile = 4*j + wv.  acc[5][16].  A staged once per tile.
// ---------------------------------------------------------------------------
__global__ __launch_bounds__(256, 4) void engram_gemm(
    const float* __restrict__ x,
    const int*   __restrict__ input_ids,
    const int*   __restrict__ mult,
    const unsigned short* __restrict__ ebf,
    const float* __restrict__ val_b,
    const float* __restrict__ key_b,
    const float* __restrict__ normq_w,
    const float* __restrict__ normk_w,
    const unsigned short* __restrict__ WbF,
    float* __restrict__ v_base,
    float* __restrict__ Gbuf,
    float* __restrict__ S2buf)
{
    __shared__ int   sids[32][4];
    __shared__ short AD[32 * 260];   // 16640 B; reused as f32 D[32][130]

    const int tid  = threadIdx.x;
    const int tok0 = blockIdx.x << 5;

    if (tid < 32) {
        int token = tok0 + tid;
        int b = token >> 12, t = token & 4095;
        const int* row = input_ids + (b << 12);
        unsigned g2 = (unsigned)row[t];
        unsigned g1 = (t >= 1) ? (unsigned)row[t - 1] : 0u;
        unsigned g0 = (t >= 2) ? (unsigned)row[t - 2] : 0u;
        sids[tid][0] = (int)(((g1 * (unsigned)mult[0]) ^ (g2 * (unsigned)mult[1])) & 4095u);
        sids[tid][1] = (int)((((g1 * (unsigned)mult[3]) ^ (g2 * (unsigned)mult[4])) & 4095u) + 4096u);
        sids[tid][2] = (int)((((g0 * (unsigned)mult[6]) ^ (g1 * (unsigned)mult[7]) ^ (g2 * (unsigned)mult[8])) & 4095u) + 8192u);
        sids[tid][3] = (int)((((g0 * (unsigned)mult[9]) ^ (g1 * (unsigned)mult[10]) ^ (g2 * (unsigned)mult[11])) & 4095u) + 12288u);
    }
    __syncthreads();

    // ---- stage A: 32 tokens x 32 chunks(8 bf16) = 1024 -> 4 per thread
    #pragma unroll
    for (int it = 0; it < 4; ++it) {
        int f = (it << 8) + tid;
        int token = f >> 5, ch = f & 31;
        const unsigned short* src = ebf + ((size_t)sids[token][ch >> 3] << 6) + ((ch & 7) << 3);
        short4v lo = *(const short4v*)src;
        short4v hi = *(const short4v*)(src + 4);
        short* dst = AD + token * 260 + (ch << 3);
        *(short4v*)dst       = lo;
        *(short4v*)(dst + 4) = hi;
    }
    __syncthreads();

    // ---- K-loop
    const int lane = tid & 63;
    const int wv   = tid >> 6;
    const int half = lane >> 5;
    const int mrow = lane & 31;

    const short*  Ap = AD + mrow * 260 + (half << 3);
    const float4* Bf = (const float4*)WbF + lane;

    floatx16 acc[5];
    #pragma unroll
    for (int j = 0; j < 5; ++j)
        #pragma unroll
        for (int r = 0; r < 16; ++r) acc[j][r] = 0.f;

    #pragma unroll 2
    for (int ks = 0; ks < 16; ++ks) {
        short4v al = *(const short4v*)(Ap + (ks << 4));
        short4v ah = *(const short4v*)(Ap + (ks << 4) + 4);
        short8 a = { al[0], al[1], al[2], al[3], ah[0], ah[1], ah[2], ah[3] };
        #pragma unroll
        for (int j = 0; j < 5; ++j) {
            union { float4 f; short8 s; } ub;
            ub.f = Bf[(size_t)((((wv + (j << 2)) << 4) + ks) << 6)];
            acc[j] = __builtin_amdgcn_mfma_f32_32x32x16_bf16(a, ub.s, acc[j], 0, 0, 0);
        }
    }

    // ---- per-chunk: D -> LDS -> epilogue
    const int ty = tid >> 4, tx = tid & 15;
    const int tx8 = tx << 3;
    float* D = (float*)AD;
    const int colw = (wv << 5) + mrow;
    const int rb   = half << 2;

    #pragma unroll
    for (int c = 0; c < 5; ++c) {
        // prefetch x (c<4) into regs BEFORE barriers: stays in flight across them
        float4 xa0, xb0, xa1, xb1;
        if (c < 4) {
            const float* xp0 = x + ((((size_t)(tok0 + (ty << 1))     << 2) + c) << 7) + tx8;
            const float* xp1 = x + ((((size_t)(tok0 + (ty << 1) + 1) << 2) + c) << 7) + tx8;
            xa0 = ld4(xp0); xb0 = ld4(xp0 + 4);
            xa1 = ld4(xp1); xb1 = ld4(xp1 + 4);
        }
        __syncthreads();   // previous chunk's D reads (or A reads) done
        #pragma unroll
        for (int r = 0; r < 16; ++r) {
            int row = (r & 3) + ((r >> 2) << 3) + rb;
            D[row * 130 + colw] = acc[c][r];
        }
        __syncthreads();

        if (c < 4) {
            const int s = c;
            const float* kbp = key_b   + (s << 7) + tx8;
            const float* nqp = normq_w + (s << 7) + tx8;
            const float* nkp = normk_w + (s << 7) + tx8;
            float4 kba = ld4(kbp), kbb = ld4(kbp + 4);
            float4 nqa = ld4(nqp), nqb = ld4(nqp + 4);
            float4 nka = ld4(nkp), nkb = ld4(nkp + 4);
            float kb[8] = {kba.x, kba.y, kba.z, kba.w, kbb.x, kbb.y, kbb.z, kbb.w};
            float nq[8] = {nqa.x, nqa.y, nqa.z, nqa.w, nqb.x, nqb.y, nqb.z, nqb.w};
            float nk[8] = {nka.x, nka.y, nka.z, nka.w, nkb.x, nkb.y, nkb.z, nkb.w};
            #pragma unroll
            for (int j = 0; j < 2; ++j) {
                int t_loc = (ty << 1) + j;
                int token = tok0 + t_loc;
                const float* dp = D + t_loc * 130 + tx8;
                float kr[8]; float ks2 = 0.f;
                #pragma unroll
                for (int m = 0; m < 8; ++m) { kr[m] = dp[m] + kb[m]; ks2 += kr[m] * kr[m]; }
                float xv[8];
                if (j == 0) { xv[0]=xa0.x; xv[1]=xa0.y; xv[2]=xa0.z; xv[3]=xa0.w;
                              xv[4]=xb0.x; xv[5]=xb0.y; xv[6]=xb0.z; xv[7]=xb0.w; }
                else        { xv[0]=xa1.x; xv[1]=xa1.y; xv[2]=xa1.z; xv[3]=xa1.w;
                              xv[4]=xb1.x; xv[5]=xb1.y; xv[6]=xb1.z; xv[7]=xb1.w; }
                float xs2 = 0.f, dt = 0.f;
                #pragma unroll
                for (int m = 0; m < 8; ++m) { xs2 += xv[m] * xv[m]; dt += xv[m] * nq[m] * kr[m] * nk[m]; }
                #pragma unroll
                for (int off = 1; off < 16; off <<= 1) {
                    ks2 += __shfl_xor(ks2, off);
                    xs2 += __shfl_xor(xs2, off);
                    dt  += __shfl_xor(dt,  off);
                }
                float sc = dt * rsqrtf(xs2 * (1.f / 128.f) + EPS)
                              * rsqrtf(ks2 * (1.f / 128.f) + EPS) * 0.08838834764831845f;
                float gate = 1.f / (1.f + __expf(-sc));
                if (tx == 0) Gbuf[(token << 2) + s] = gate;
            }
        } else {
            const float* vbp = val_b + tx8;
            float4 vba = ld4(vbp), vbb = ld4(vbp + 4);
            float vb[8] = {vba.x, vba.y, vba.z, vba.w, vbb.x, vbb.y, vbb.z, vbb.w};
            #pragma unroll
            for (int j = 0; j < 2; ++j) {
                int t_loc = (ty << 1) + j;
                int token = tok0 + t_loc;
                const float* dp = D + t_loc * 130 + tx8;
                float v[8]; float s2 = 0.f;
                #pragma unroll
                for (int m = 0; m < 8; ++m) { v[m] = dp[m] + vb[m]; s2 += v[m] * v[m]; }
                #pragma unroll
                for (int off = 1; off < 16; off <<= 1) s2 += __shfl_xor(s2, off);
                float* vp = v_base + ((size_t)token << 7) + tx8;
                st4(vp,     make_float4(v[0], v[1], v[2], v[3]));
                st4(vp + 4, make_float4(v[4], v[5], v[6], v[7]));
                if (tx == 0) S2buf[token] = s2;
            }
        }
    }
}

// ---------------------------------------------------------------------------
// Kernel 3: fused gate/xn/conv/SiLU/residual epilogue (native exp)
// ---------------------------------------------------------------------------
__global__ __launch_bounds__(256) void engram_out(
    const float* __restrict__ v_base,
    const float* __restrict__ Gbuf,
    const float* __restrict__ S2buf,
    const float* __restrict__ conv_w,
    const float* __restrict__ convnorm_w,
    float* __restrict__ out)
{
    int idx   = blockIdx.x * 256 + threadIdx.x;   // < 1048576
    int d4    = idx & 31;
    int token = idx >> 5;
    int t     = token & 4095;

    float vw[4][4];
    float fwin[4][4];
    float gcur[4];
    #pragma unroll
    for (int k = 0; k < 4; ++k) {
        int tt = t + k - 3;
        if (tt >= 0) {
            int tok2 = token + k - 3;
            float4 v = ld4(v_base + ((size_t)tok2 << 7) + (d4 << 2));
            vw[k][0] = v.x; vw[k][1] = v.y; vw[k][2] = v.z; vw[k][3] = v.w;
            float s2n = S2buf[tok2] * (1.f / 128.f);
            #pragma unroll
            for (int s = 0; s < 4; ++s) {
                float g = Gbuf[(tok2 << 2) + s];
                fwin[k][s] = g * rsqrtf(g * g * s2n + EPS);
                if (k == 3) gcur[s] = g;
            }
        } else {
            #pragma unroll
            for (int i = 0; i < 4; ++i) vw[k][i] = 0.f;
            #pragma unroll
            for (int s = 0; s < 4; ++s) fwin[k][s] = 0.f;
        }
    }

    #pragma unroll
    for (int s = 0; s < 4; ++s) {
        float4 cwv = ld4(convnorm_w + (s << 7) + (d4 << 2));
        float cw[4] = {cwv.x, cwv.y, cwv.z, cwv.w};
        float o[4];
        #pragma unroll
        for (int i = 0; i < 4; ++i) {
            const float* wp = conv_w + (size_t)(((s << 7) + (d4 << 2) + i) << 2);
            float4 w = ld4(wp);
            float a = w.x * vw[0][i] * fwin[0][s]
                    + w.y * vw[1][i] * fwin[1][s]
                    + w.z * vw[2][i] * fwin[2][s]
                    + w.w * vw[3][i] * fwin[3][s];
            float y = a * cw[i];
            o[i] = vw[3][i] * gcur[s] + y / (1.f + __expf(-y));
        }
        st4(out + ((size_t)((token << 2) + s) << 7) + (d4 << 2),
            make_float4(o[0], o[1], o[2], o[3]));
    }
}

// ---------------------------------------------------------------------------
extern "C" void kernel_launch(void* const* d_in, const int* in_sizes, int n_in,
                              void* d_out, int out_size, void* d_ws, size_t ws_size,
                              hipStream_t stream)
{
    const float* x          = (const float*)d_in[0];
    const int*   input_ids  = (const int*)d_in[1];
    const int*   mult       = (const int*)d_in[2];
    const float* embedding  = (const float*)d_in[3];
    const float* val_W      = (const float*)d_in[4];
    const float* val_b      = (const float*)d_in[5];
    const float* key_W      = (const float*)d_in[6];
    const float* key_b      = (const float*)d_in[7];
    const float* normq_w    = (const float*)d_in[8];
    const float* normk_w    = (const float*)d_in[9];
    const float* conv_w     = (const float*)d_in[10];
    const float* convnorm_w = (const float*)d_in[11];
    float* out = (float*)d_out;

    char* ws = (char*)d_ws;
    unsigned short* WbF = (unsigned short*)ws;                    // 327,680 B
    unsigned short* ebf = (unsigned short*)(ws + 327680);         // 2,097,152 B
    float* v_base = (float*)(ws + 327680 + 2097152);              // 16 MiB
    float* Gbuf   = (float*)(ws + 327680 + 2097152 + 16777216);   // 512 KiB
    float* S2buf  = (float*)(ws + 327680 + 2097152 + 16777216 + 524288); // 128 KiB

    build_wb<<<80, 256, 0, stream>>>(val_W, key_W, WbF);
    build_ebf<<<512, 256, 0, stream>>>(embedding, ebf);
    engram_gemm<<<1024, 256, 0, stream>>>(x, input_ids, mult, ebf, val_b, key_b,
                                          normq_w, normk_w, WbF, v_base, Gbuf, S2buf);
    engram_out<<<4096, 256, 0, stream>>>(v_base, Gbuf, S2buf, conv_w, convnorm_w, out);
}

// Round 5
// 172.266 us; speedup vs baseline: 1.0793x; 1.0793x over previous
//
#include <hip/hip_runtime.h>
#include <math.h>

#define EPS 1.1920928955078125e-07f   // jnp.finfo(f32).eps

typedef __attribute__((ext_vector_type(8)))  short short8;
typedef __attribute__((ext_vector_type(4)))  short short4v;
typedef __attribute__((ext_vector_type(16))) float floatx16;

__device__ __forceinline__ float4 ld4(const float* __restrict__ p) { return *(const float4* __restrict__)p; }
__device__ __forceinline__ void   st4(float* __restrict__ p, float4 v) { *(float4* __restrict__)p = v; }

// f32 -> bf16 round-to-nearest-even
__device__ __forceinline__ unsigned short f2bf(float f) {
    union { float f; unsigned u; } v; v.f = f;
    unsigned r = v.u + 0x7fffu + ((v.u >> 16) & 1u);
    return (unsigned short)(r >> 16);
}

// ---------------------------------------------------------------------------
// Kernel 1: pack W (MFMA B-frag layout) + embedding->bf16, one launch.
// blocks 0..79: WbF; blocks 80..591: ebf
// ---------------------------------------------------------------------------
__global__ __launch_bounds__(256) void build_pack(const float* __restrict__ val_W,
                                                  const float* __restrict__ key_W,
                                                  const float* __restrict__ emb,
                                                  unsigned short* __restrict__ WbF,
                                                  unsigned short* __restrict__ ebf)
{
    int bid = blockIdx.x;
    if (bid < 80) {
        int idx  = bid * 256 + threadIdx.x;           // 0 .. 20479
        int lane = idx & 63;
        int ks   = (idx >> 6) & 15;
        int nt   = idx >> 10;
        int n = (nt << 5) + (lane & 31);
        int k = (ks << 4) + ((lane >> 5) << 3);
        const float* src = (n < 512) ? key_W + (size_t)n * 256 + k
                                     : val_W + (size_t)(n - 512) * 256 + k;
        float4 v0 = ld4(src), v1 = ld4(src + 4);
        unsigned short o[8] = { f2bf(v0.x), f2bf(v0.y), f2bf(v0.z), f2bf(v0.w),
                                f2bf(v1.x), f2bf(v1.y), f2bf(v1.z), f2bf(v1.w) };
        unsigned short* dst = WbF + (size_t)idx * 8;
        *(short4v*)dst       = *(short4v*)&o[0];
        *(short4v*)(dst + 4) = *(short4v*)&o[4];
    } else {
        int idx = (bid - 80) * 256 + threadIdx.x;     // < 131072
        const float* src = emb + ((size_t)idx << 3);
        float4 v0 = ld4(src), v1 = ld4(src + 4);
        unsigned short o[8] = { f2bf(v0.x), f2bf(v0.y), f2bf(v0.z), f2bf(v0.w),
                                f2bf(v1.x), f2bf(v1.y), f2bf(v1.z), f2bf(v1.w) };
        unsigned short* dst = ebf + ((size_t)idx << 3);
        *(short4v*)dst       = *(short4v*)&o[0];
        *(short4v*)(dst + 4) = *(short4v*)&o[4];
    }
}

// ---------------------------------------------------------------------------
// Kernel 2: hash + gather(bf16) + MFMA GEMM, 32-token tile, chunk-split 3 ways
// grid 3072: part = bid>>10 (0:{0,1} 1:{2,3} 2:{4}), tile = bid&1023
// ---------------------------------------------------------------------------
__global__ __launch_bounds__(256, 6) void engram_gemm(
    const float* __restrict__ x,
    const int*   __restrict__ input_ids,
    const int*   __restrict__ mult,
    const unsigned short* __restrict__ ebf,
    const float* __restrict__ val_b,
    const float* __restrict__ key_b,
    const float* __restrict__ normq_w,
    const float* __restrict__ normk_w,
    const unsigned short* __restrict__ WbF,
    float* __restrict__ v_base,
    float* __restrict__ Gbuf,
    float* __restrict__ S2buf)
{
    __shared__ int   sids[32][4];
    __shared__ short AD[32 * 260];   // bf16 A [32][260]; reused as f32 D[32][130]

    const int tid  = threadIdx.x;
    const int part = blockIdx.x >> 10;
    const int tok0 = (blockIdx.x & 1023) << 5;

    if (tid < 32) {
        int token = tok0 + tid;
        int b = token >> 12, t = token & 4095;
        const int* row = input_ids + (b << 12);
        unsigned g2 = (unsigned)row[t];
        unsigned g1 = (t >= 1) ? (unsigned)row[t - 1] : 0u;
        unsigned g0 = (t >= 2) ? (unsigned)row[t - 2] : 0u;
        sids[tid][0] = (int)(((g1 * (unsigned)mult[0]) ^ (g2 * (unsigned)mult[1])) & 4095u);
        sids[tid][1] = (int)((((g1 * (unsigned)mult[3]) ^ (g2 * (unsigned)mult[4])) & 4095u) + 4096u);
        sids[tid][2] = (int)((((g0 * (unsigned)mult[6]) ^ (g1 * (unsigned)mult[7]) ^ (g2 * (unsigned)mult[8])) & 4095u) + 8192u);
        sids[tid][3] = (int)((((g0 * (unsigned)mult[9]) ^ (g1 * (unsigned)mult[10]) ^ (g2 * (unsigned)mult[11])) & 4095u) + 12288u);
    }
    __syncthreads();

    // stage A: 32 tokens x 32 chunks(8 bf16) -> 4 per thread
    #pragma unroll
    for (int it = 0; it < 4; ++it) {
        int f = (it << 8) + tid;
        int token = f >> 5, ch = f & 31;
        const unsigned short* src = ebf + ((size_t)sids[token][ch >> 3] << 6) + ((ch & 7) << 3);
        short4v lo = *(const short4v*)src;
        short4v hi = *(const short4v*)(src + 4);
        short* dst = AD + token * 260 + (ch << 3);
        *(short4v*)dst       = lo;
        *(short4v*)(dst + 4) = hi;
    }
    __syncthreads();

    const int lane = tid & 63;
    const int wv   = tid >> 6;
    const int half = lane >> 5;
    const int mrow = lane & 31;

    const short*  Ap = AD + mrow * 260 + (half << 3);
    const float4* Bf = (const float4*)WbF + lane;

    const int ty = tid >> 4, tx = tid & 15;
    const int tx8 = tx << 3;
    float* D = (float*)AD;
    const int colw = (wv << 5) + mrow;
    const int rb   = half << 2;

    if (part < 2) {
        const int c0 = part << 1;
        floatx16 acc[2];
        #pragma unroll
        for (int r = 0; r < 16; ++r) { acc[0][r] = 0.f; acc[1][r] = 0.f; }

        #pragma unroll 2
        for (int ks = 0; ks < 16; ++ks) {
            short4v al = *(const short4v*)(Ap + (ks << 4));
            short4v ah = *(const short4v*)(Ap + (ks << 4) + 4);
            short8 a = { al[0], al[1], al[2], al[3], ah[0], ah[1], ah[2], ah[3] };
            #pragma unroll
            for (int j = 0; j < 2; ++j) {
                int nt = ((c0 + j) << 2) + wv;
                union { float4 f; short8 s; } ub;
                ub.f = Bf[(size_t)(((nt << 4) + ks) << 6)];
                acc[j] = __builtin_amdgcn_mfma_f32_32x32x16_bf16(a, ub.s, acc[j], 0, 0, 0);
            }
        }

        #pragma unroll
        for (int j = 0; j < 2; ++j) {
            const int s = c0 + j;
            // prefetch x before the barriers (stays in flight across them)
            const float* xp0 = x + ((((size_t)(tok0 + (ty << 1))     << 2) + s) << 7) + tx8;
            const float* xp1 = x + ((((size_t)(tok0 + (ty << 1) + 1) << 2) + s) << 7) + tx8;
            float4 xa0 = ld4(xp0), xb0 = ld4(xp0 + 4);
            float4 xa1 = ld4(xp1), xb1 = ld4(xp1 + 4);
            __syncthreads();
            #pragma unroll
            for (int r = 0; r < 16; ++r) {
                int row = (r & 3) + ((r >> 2) << 3) + rb;
                D[row * 130 + colw] = acc[j][r];
            }
            __syncthreads();

            const float* kbp = key_b   + (s << 7) + tx8;
            const float* nqp = normq_w + (s << 7) + tx8;
            const float* nkp = normk_w + (s << 7) + tx8;
            float4 kba = ld4(kbp), kbb = ld4(kbp + 4);
            float4 nqa = ld4(nqp), nqb = ld4(nqp + 4);
            float4 nka = ld4(nkp), nkb = ld4(nkp + 4);
            float kb[8] = {kba.x, kba.y, kba.z, kba.w, kbb.x, kbb.y, kbb.z, kbb.w};
            float nq[8] = {nqa.x, nqa.y, nqa.z, nqa.w, nqb.x, nqb.y, nqb.z, nqb.w};
            float nk[8] = {nka.x, nka.y, nka.z, nka.w, nkb.x, nkb.y, nkb.z, nkb.w};
            #pragma unroll
            for (int jj = 0; jj < 2; ++jj) {
                int t_loc = (ty << 1) + jj;
                int token = tok0 + t_loc;
                const float* dp = D + t_loc * 130 + tx8;
                float kr[8]; float ks2 = 0.f;
                #pragma unroll
                for (int m = 0; m < 8; ++m) { kr[m] = dp[m] + kb[m]; ks2 += kr[m] * kr[m]; }
                float xv[8];
                if (jj == 0) { xv[0]=xa0.x; xv[1]=xa0.y; xv[2]=xa0.z; xv[3]=xa0.w;
                               xv[4]=xb0.x; xv[5]=xb0.y; xv[6]=xb0.z; xv[7]=xb0.w; }
                else         { xv[0]=xa1.x; xv[1]=xa1.y; xv[2]=xa1.z; xv[3]=xa1.w;
                               xv[4]=xb1.x; xv[5]=xb1.y; xv[6]=xb1.z; xv[7]=xb1.w; }
                float xs2 = 0.f, dt = 0.f;
                #pragma unroll
                for (int m = 0; m < 8; ++m) { xs2 += xv[m] * xv[m]; dt += xv[m] * nq[m] * kr[m] * nk[m]; }
                #pragma unroll
                for (int off = 1; off < 16; off <<= 1) {
                    ks2 += __shfl_xor(ks2, off);
                    xs2 += __shfl_xor(xs2, off);
                    dt  += __shfl_xor(dt,  off);
                }
                float sc = dt * rsqrtf(xs2 * (1.f / 128.f) + EPS)
                              * rsqrtf(ks2 * (1.f / 128.f) + EPS) * 0.08838834764831845f;
                float gate = 1.f / (1.f + __expf(-sc));
                if (tx == 0) Gbuf[(token << 2) + s] = gate;
            }
        }
    } else {
        floatx16 acc;
        #pragma unroll
        for (int r = 0; r < 16; ++r) acc[r] = 0.f;
        #pragma unroll 4
        for (int ks = 0; ks < 16; ++ks) {
            short4v al = *(const short4v*)(Ap + (ks << 4));
            short4v ah = *(const short4v*)(Ap + (ks << 4) + 4);
            short8 a = { al[0], al[1], al[2], al[3], ah[0], ah[1], ah[2], ah[3] };
            int nt = 16 + wv;
            union { float4 f; short8 s; } ub;
            ub.f = Bf[(size_t)(((nt << 4) + ks) << 6)];
            acc = __builtin_amdgcn_mfma_f32_32x32x16_bf16(a, ub.s, acc, 0, 0, 0);
        }
        __syncthreads();
        #pragma unroll
        for (int r = 0; r < 16; ++r) {
            int row = (r & 3) + ((r >> 2) << 3) + rb;
            D[row * 130 + colw] = acc[r];
        }
        __syncthreads();

        const float* vbp = val_b + tx8;
        float4 vba = ld4(vbp), vbb = ld4(vbp + 4);
        float vb[8] = {vba.x, vba.y, vba.z, vba.w, vbb.x, vbb.y, vbb.z, vbb.w};
        #pragma unroll
        for (int jj = 0; jj < 2; ++jj) {
            int t_loc = (ty << 1) + jj;
            int token = tok0 + t_loc;
            const float* dp = D + t_loc * 130 + tx8;
            float v[8]; float s2 = 0.f;
            #pragma unroll
            for (int m = 0; m < 8; ++m) { v[m] = dp[m] + vb[m]; s2 += v[m] * v[m]; }
            #pragma unroll
            for (int off = 1; off < 16; off <<= 1) s2 += __shfl_xor(s2, off);
            float* vp = v_base + ((size_t)token << 7) + tx8;
            st4(vp,     make_float4(v[0], v[1], v[2], v[3]));
            st4(vp + 4, make_float4(v[4], v[5], v[6], v[7]));
            if (tx == 0) S2buf[token] = s2;
        }
    }
}

// ---------------------------------------------------------------------------
// Kernel 3: gate/xn/conv/SiLU/residual. thread = (4-token group, stream-pair, d4)
// window rows reused across 4 tokens and 2 streams. grid 2048 x 256.
// ---------------------------------------------------------------------------
__global__ __launch_bounds__(256, 4) void engram_out(
    const float* __restrict__ v_base,
    const float* __restrict__ Gbuf,
    const float* __restrict__ S2buf,
    const float* __restrict__ conv_w,
    const float* __restrict__ convnorm_w,
    float* __restrict__ out)
{
    int idx  = blockIdx.x * 256 + threadIdx.x;   // < 524288
    int d4   = idx & 31;
    int sp   = (idx >> 5) & 1;
    int grp  = idx >> 6;                          // 0..8191
    int tg0  = grp << 2;                          // first output token
    int tsq0 = tg0 & 4095;
    int s0   = sp << 1;

    float v[7][4];
    float fw[7][2];
    float gq[4][2];
    #pragma unroll
    for (int j = 0; j < 7; ++j) {
        if (tsq0 + j >= 3) {
            int glob = tg0 - 3 + j;
            float4 vv = ld4(v_base + ((size_t)glob << 7) + (d4 << 2));
            v[j][0] = vv.x; v[j][1] = vv.y; v[j][2] = vv.z; v[j][3] = vv.w;
            float s2n = S2buf[glob] * (1.f / 128.f);
            #pragma unroll
            for (int q = 0; q < 2; ++q) {
                float g = Gbuf[(glob << 2) + s0 + q];
                fw[j][q] = g * rsqrtf(g * g * s2n + EPS);
                if (j >= 3) gq[j - 3][q] = g;
            }
        } else {
            #pragma unroll
            for (int i = 0; i < 4; ++i) v[j][i] = 0.f;
            fw[j][0] = 0.f; fw[j][1] = 0.f;
        }
    }

    float4 w[2][4];
    float  cw[2][4];
    #pragma unroll
    for (int q = 0; q < 2; ++q) {
        float4 c = ld4(convnorm_w + ((s0 + q) << 7) + (d4 << 2));
        cw[q][0] = c.x; cw[q][1] = c.y; cw[q][2] = c.z; cw[q][3] = c.w;
        #pragma unroll
        for (int i = 0; i < 4; ++i)
            w[q][i] = ld4(conv_w + (size_t)(((((s0 + q) << 7) + (d4 << 2) + i)) << 2));
    }

    #pragma unroll
    for (int t = 0; t < 4; ++t) {
        int glob = tg0 + t;
        #pragma unroll
        for (int q = 0; q < 2; ++q) {
            float o[4];
            #pragma unroll
            for (int i = 0; i < 4; ++i) {
                float a = w[q][i].x * v[t][i]     * fw[t][q]
                        + w[q][i].y * v[t + 1][i] * fw[t + 1][q]
                        + w[q][i].z * v[t + 2][i] * fw[t + 2][q]
                        + w[q][i].w * v[t + 3][i] * fw[t + 3][q];
                float y = a * cw[q][i];
                o[i] = v[t + 3][i] * gq[t][q] + y / (1.f + __expf(-y));
            }
            st4(out + ((size_t)((glob << 2) + s0 + q) << 7) + (d4 << 2),
                make_float4(o[0], o[1], o[2], o[3]));
        }
    }
}

// ---------------------------------------------------------------------------
extern "C" void kernel_launch(void* const* d_in, const int* in_sizes, int n_in,
                              void* d_out, int out_size, void* d_ws, size_t ws_size,
                              hipStream_t stream)
{
    const float* x          = (const float*)d_in[0];
    const int*   input_ids  = (const int*)d_in[1];
    const int*   mult       = (const int*)d_in[2];
    const float* embedding  = (const float*)d_in[3];
    const float* val_W      = (const float*)d_in[4];
    const float* val_b      = (const float*)d_in[5];
    const float* key_W      = (const float*)d_in[6];
    const float* key_b      = (const float*)d_in[7];
    const float* normq_w    = (const float*)d_in[8];
    const float* normk_w    = (const float*)d_in[9];
    const float* conv_w     = (const float*)d_in[10];
    const float* convnorm_w = (const float*)d_in[11];
    float* out = (float*)d_out;

    char* ws = (char*)d_ws;
    unsigned short* WbF = (unsigned short*)ws;                    // 327,680 B
    unsigned short* ebf = (unsigned short*)(ws + 327680);         // 2,097,152 B
    float* v_base = (float*)(ws + 327680 + 2097152);              // 16 MiB
    float* Gbuf   = (float*)(ws + 327680 + 2097152 + 16777216);   // 512 KiB
    float* S2buf  = (float*)(ws + 327680 + 2097152 + 16777216 + 524288); // 128 KiB

    build_pack<<<592, 256, 0, stream>>>(val_W, key_W, embedding, WbF, ebf);
    engram_gemm<<<3072, 256, 0, stream>>>(x, input_ids, mult, ebf, val_b, key_b,
                                          normq_w, normk_w, WbF, v_base, Gbuf, S2buf);
    engram_out<<<2048, 256, 0, stream>>>(v_base, Gbuf, S2buf, conv_w, convnorm_w, out);
}